// Round 1
// baseline (102.035 us; speedup 1.0000x reference)
//
#include <hip/hip_runtime.h>
#include <hip/hip_bf16.h>

// Problem constants (from reference): x [1024, 2048] fp32 binary, Q [2048, 2048] fp32.
// out[i] = x_i @ Q @ x_i  (1024 fp32 scalars).
// Identity used: x^T Q x == x^T Q^T x, so GEMM B-operand = Q^T, whose B^T (N x K)
// layout for MFMA is exactly row-major Q. No transpose needed.

#define B_ROWS 1024
#define N_BITS 2048

#define BM 128
#define BN 128
#define BK 32
#define KSPLIT 4
#define KPER (N_BITS / KSPLIT)   // 512
#define KITERS (KPER / BK)       // 16

typedef __bf16 bf16_t;
typedef __bf16 bf16x8 __attribute__((ext_vector_type(8)));
typedef float f32x4 __attribute__((ext_vector_type(4)));

__device__ __forceinline__ void load16_to_lds(const void* g, void* l) {
  __builtin_amdgcn_global_load_lds(
      (__attribute__((address_space(1))) void*)(g),
      (__attribute__((address_space(3))) void*)(l),
      16, 0, 0);
}

// prep: convert x (2M elems) and Q (4M elems) fp32 -> bf16 into ws; zero out[1024].
__global__ __launch_bounds__(256) void prep_kernel(
    const float* __restrict__ x, const float* __restrict__ Q,
    bf16_t* __restrict__ xb, bf16_t* __restrict__ qb, float* __restrict__ out) {
  const int tid = blockIdx.x * 256 + threadIdx.x;
  if (tid < B_ROWS) out[tid] = 0.0f;
  const int XTH = (B_ROWS * N_BITS) / 8;  // 262144 threads cover x
  const float* src;
  bf16_t* dst;
  if (tid < XTH) {
    size_t o = (size_t)tid * 8;
    src = x + o;
    dst = xb + o;
  } else {
    size_t o = (size_t)(tid - XTH) * 8;
    src = Q + o;
    dst = qb + o;
  }
  float4 v0 = ((const float4*)src)[0];
  float4 v1 = ((const float4*)src)[1];
  union { int4 i4; __hip_bfloat16 h[8]; } u;
  u.h[0] = __float2bfloat16(v0.x);
  u.h[1] = __float2bfloat16(v0.y);
  u.h[2] = __float2bfloat16(v0.z);
  u.h[3] = __float2bfloat16(v0.w);
  u.h[4] = __float2bfloat16(v1.x);
  u.h[5] = __float2bfloat16(v1.y);
  u.h[6] = __float2bfloat16(v1.z);
  u.h[7] = __float2bfloat16(v1.w);
  ((int4*)dst)[0] = u.i4;
}

// Fused GEMM (S' = Xb @ Qb^T via MFMA) + row-dot with fp32 x + atomicAdd to out.
// Block: 256 threads = 4 waves in 2x2, each wave does 64x64 via 4x4 MFMA 16x16x32.
__global__ __launch_bounds__(256) void qubo_kernel(
    const bf16_t* __restrict__ Xb, const bf16_t* __restrict__ Qb,
    const float* __restrict__ xf, float* __restrict__ out) {
  __shared__ bf16_t ldsA[BM * BK];
  __shared__ bf16_t ldsB[BN * BK];

  const int tid  = threadIdx.x;
  const int lane = tid & 63;
  const int wave = tid >> 6;     // 0..3
  const int wr   = wave >> 1;    // wave row group (0..1)
  const int wc   = wave & 1;     // wave col group (0..1)
  const int lrow = lane & 15;    // m/n within 16
  const int quad = lane >> 4;    // 0..3  (k-chunk for A/B frags, row-quad for C/D)

  const int m0    = blockIdx.y * BM;
  const int n0    = blockIdx.x * BN;
  const int kbase = blockIdx.z * KPER;

  // staging: each thread loads one 16B chunk per pass; wave-contiguous LDS dest
  // (lds offset == wave_base + lane*16) as global_load_lds requires.
  const int srow = tid >> 2;        // 0..63 (row within 64-row pass)
  const int sc16 = (tid & 3) * 8;   // bf16 element offset (8 elems = 16 B)

  f32x4 acc[4][4];
#pragma unroll
  for (int i = 0; i < 4; ++i)
#pragma unroll
    for (int j = 0; j < 4; ++j) acc[i][j] = (f32x4){0.f, 0.f, 0.f, 0.f};

  for (int kt = 0; kt < KITERS; ++kt) {
    const int k0 = kbase + kt * BK;
#pragma unroll
    for (int p = 0; p < 2; ++p) {
      const int r = p * 64 + srow;
      load16_to_lds(Xb + (size_t)(m0 + r) * N_BITS + k0 + sc16,
                    ldsA + r * BK + sc16);
    }
#pragma unroll
    for (int p = 0; p < 2; ++p) {
      const int r = p * 64 + srow;
      load16_to_lds(Qb + (size_t)(n0 + r) * N_BITS + k0 + sc16,
                    ldsB + r * BK + sc16);
    }
    __syncthreads();  // drains vmcnt (global_load_lds) + makes LDS visible

    bf16x8 afrag[4], bfrag[4];
#pragma unroll
    for (int mi = 0; mi < 4; ++mi)
      afrag[mi] = *(const bf16x8*)&ldsA[(wr * 64 + mi * 16 + lrow) * BK + quad * 8];
#pragma unroll
    for (int ni = 0; ni < 4; ++ni)
      bfrag[ni] = *(const bf16x8*)&ldsB[(wc * 64 + ni * 16 + lrow) * BK + quad * 8];

#pragma unroll
    for (int mi = 0; mi < 4; ++mi)
#pragma unroll
      for (int ni = 0; ni < 4; ++ni)
        acc[mi][ni] = __builtin_amdgcn_mfma_f32_16x16x32_bf16(
            afrag[mi], bfrag[ni], acc[mi][ni], 0, 0, 0);

    __syncthreads();  // before next iteration overwrites LDS
  }

  // Epilogue: out[row] += sum_col S'[row,col] * x[row,col]
  // C/D layout (16x16x32): col = lane&15, row = quad*4 + reg.
#pragma unroll
  for (int mi = 0; mi < 4; ++mi) {
#pragma unroll
    for (int r = 0; r < 4; ++r) {
      const int row = m0 + wr * 64 + mi * 16 + quad * 4 + r;
      float s = 0.f;
#pragma unroll
      for (int ni = 0; ni < 4; ++ni) {
        const int col = n0 + wc * 64 + ni * 16 + lrow;
        s += acc[mi][ni][r] * xf[(size_t)row * N_BITS + col];
      }
      // reduce over the 16 lanes (lrow 0..15) sharing this row; xor<16 stays in-quad
#pragma unroll
      for (int off = 1; off < 16; off <<= 1)
        s += __shfl_xor(s, off, 64);
      if (lrow == 0) atomicAdd(&out[row], s);
    }
  }
}

extern "C" void kernel_launch(void* const* d_in, const int* in_sizes, int n_in,
                              void* d_out, int out_size, void* d_ws, size_t ws_size,
                              hipStream_t stream) {
  const float* x = (const float*)d_in[0];   // [1024, 2048] fp32 (binary)
  const float* Q = (const float*)d_in[1];   // [2048, 2048] fp32
  float* out = (float*)d_out;               // [1024] fp32

  bf16_t* xb = (bf16_t*)d_ws;                                             // 4 MB
  bf16_t* qb = (bf16_t*)((char*)d_ws + (size_t)B_ROWS * N_BITS * 2);      // 8 MB

  // 6M elements / 8 per thread / 256 per block = 3072 blocks
  prep_kernel<<<3072, 256, 0, stream>>>(x, Q, xb, qb, out);

  dim3 grid(N_BITS / BN, B_ROWS / BM, KSPLIT);  // (16, 8, 4) = 512 blocks
  qubo_kernel<<<grid, dim3(256), 0, stream>>>(xb, qb, x, out);
}

// Round 2
// 94.194 us; speedup vs baseline: 1.0832x; 1.0832x over previous
//
#include <hip/hip_runtime.h>
#include <hip/hip_bf16.h>

// out[i] = x_i @ Q @ x_i, x [1024,2048] fp32 binary, Q [2048,2048] fp32.
// Identity: x^T Q x == x^T Q^T x, so the MFMA B-operand (N x K layout) is
// row-major Q directly — no transpose.
// Round 2: KSPLIT=8 (1024 blocks, ~3 blocks/CU), BK=64 (4 barriers/block),
// XOR-swizzled LDS chunks (2-way banks, free), 4x1 wave layout (1 atomic/row/block).

#define B_ROWS 1024
#define N_BITS 2048

#define BM 128
#define BN 128
#define BK 64
#define KSPLIT 8
#define KPER (N_BITS / KSPLIT)   // 256
#define KITERS (KPER / BK)       // 4

typedef __bf16 bf16_t;
typedef __bf16 bf16x8 __attribute__((ext_vector_type(8)));
typedef float f32x4 __attribute__((ext_vector_type(4)));

__device__ __forceinline__ void load16_to_lds(const void* g, void* l) {
  __builtin_amdgcn_global_load_lds(
      (__attribute__((address_space(1))) void*)(g),
      (__attribute__((address_space(3))) void*)(l),
      16, 0, 0);
}

// prep: fp32 -> bf16 for x (2M) and Q (4M) into ws; zero out[1024].
__global__ __launch_bounds__(256) void prep_kernel(
    const float* __restrict__ x, const float* __restrict__ Q,
    bf16_t* __restrict__ xb, bf16_t* __restrict__ qb, float* __restrict__ out) {
  const int tid = blockIdx.x * 256 + threadIdx.x;
  if (tid < B_ROWS) out[tid] = 0.0f;
  const int XTH = (B_ROWS * N_BITS) / 8;
  const float* src;
  bf16_t* dst;
  if (tid < XTH) {
    size_t o = (size_t)tid * 8;
    src = x + o;
    dst = xb + o;
  } else {
    size_t o = (size_t)(tid - XTH) * 8;
    src = Q + o;
    dst = qb + o;
  }
  float4 v0 = ((const float4*)src)[0];
  float4 v1 = ((const float4*)src)[1];
  union { int4 i4; __hip_bfloat16 h[8]; } u;
  u.h[0] = __float2bfloat16(v0.x);
  u.h[1] = __float2bfloat16(v0.y);
  u.h[2] = __float2bfloat16(v0.z);
  u.h[3] = __float2bfloat16(v0.w);
  u.h[4] = __float2bfloat16(v1.x);
  u.h[5] = __float2bfloat16(v1.y);
  u.h[6] = __float2bfloat16(v1.z);
  u.h[7] = __float2bfloat16(v1.w);
  ((int4*)dst)[0] = u.i4;
}

// Fused GEMM (S = Xb @ Qb^T) + row-dot + atomicAdd.
// 4 waves split M (each owns 32 rows x BN=128): acc = 2x8 frags of 16x16x32.
__global__ __launch_bounds__(256) void qubo_kernel(
    const bf16_t* __restrict__ Xb, const bf16_t* __restrict__ Qb,
    float* __restrict__ out) {
  __shared__ bf16_t ldsA[BM * BK];   // 16 KB
  __shared__ bf16_t ldsB[BN * BK];   // 16 KB

  const int tid  = threadIdx.x;
  const int lane = tid & 63;
  const int wave = tid >> 6;     // 0..3 -> owns rows [wave*32, wave*32+32)
  const int lrow = lane & 15;
  const int quad = lane >> 4;

  const int m0    = blockIdx.y * BM;
  const int n0    = blockIdx.x * BN;
  const int kbase = blockIdx.z * KPER;

  // Staging: 256 threads x 16 B = 32 rows/pass; 4 passes per 128-row tile.
  // LDS dest is linear (wave_base + lane*16 — required by global_load_lds);
  // the GLOBAL chunk is XOR-swizzled per row so that the later ds_read_b128
  // frag reads land 2 lanes/bank (free) instead of 16-way conflicted.
  const int srow = tid >> 3;              // 0..31
  const int cLds = tid & 7;               // chunk slot in LDS row
  const int scol = (cLds ^ (srow & 7)) * 8;  // swizzled global col (bf16 elems)
  const int sdst = cLds * 8;              // lds col (bf16 elems)

  f32x4 acc[2][8];
#pragma unroll
  for (int i = 0; i < 2; ++i)
#pragma unroll
    for (int j = 0; j < 8; ++j) acc[i][j] = (f32x4){0.f, 0.f, 0.f, 0.f};

  for (int kt = 0; kt < KITERS; ++kt) {
    const int k0 = kbase + kt * BK;
#pragma unroll
    for (int p = 0; p < 4; ++p) {
      const int r = p * 32 + srow;
      load16_to_lds(Xb + (size_t)(m0 + r) * N_BITS + k0 + scol,
                    ldsA + r * BK + sdst);
    }
#pragma unroll
    for (int p = 0; p < 4; ++p) {
      const int r = p * 32 + srow;
      load16_to_lds(Qb + (size_t)(n0 + r) * N_BITS + k0 + scol,
                    ldsB + r * BK + sdst);
    }
    __syncthreads();

    const int sw = lrow & 7;  // row&7 for all rows this lane reads
#pragma unroll
    for (int ks = 0; ks < 2; ++ks) {
      const int ch = ((ks * 4 + quad) ^ sw) * 8;  // swizzled chunk offset
      bf16x8 a[2], b[8];
#pragma unroll
      for (int mi = 0; mi < 2; ++mi)
        a[mi] = *(const bf16x8*)&ldsA[(wave * 32 + mi * 16 + lrow) * BK + ch];
#pragma unroll
      for (int ni = 0; ni < 8; ++ni)
        b[ni] = *(const bf16x8*)&ldsB[(ni * 16 + lrow) * BK + ch];
#pragma unroll
      for (int mi = 0; mi < 2; ++mi)
#pragma unroll
        for (int ni = 0; ni < 8; ++ni)
          acc[mi][ni] = __builtin_amdgcn_mfma_f32_16x16x32_bf16(
              a[mi], b[ni], acc[mi][ni], 0, 0, 0);
    }
    __syncthreads();
  }

  // Epilogue: out[row] += sum_col S[row,col] * x[row,col] over this block's
  // n-slice. C/D layout: col = lane&15, row = quad*4 + reg. Each row is owned
  // by exactly one wave -> one atomic per row per block.
#pragma unroll
  for (int mi = 0; mi < 2; ++mi) {
#pragma unroll
    for (int r = 0; r < 4; ++r) {
      const int row = m0 + wave * 32 + mi * 16 + quad * 4 + r;
      float s = 0.f;
#pragma unroll
      for (int ni = 0; ni < 8; ++ni) {
        const int col = n0 + ni * 16 + lrow;
        s += acc[mi][ni][r] * (float)Xb[(size_t)row * N_BITS + col];  // exact: binary
      }
#pragma unroll
      for (int off = 1; off < 16; off <<= 1)
        s += __shfl_xor(s, off, 64);
      if (lrow == 0) atomicAdd(&out[row], s);
    }
  }
}

extern "C" void kernel_launch(void* const* d_in, const int* in_sizes, int n_in,
                              void* d_out, int out_size, void* d_ws, size_t ws_size,
                              hipStream_t stream) {
  const float* x = (const float*)d_in[0];
  const float* Q = (const float*)d_in[1];
  float* out = (float*)d_out;

  bf16_t* xb = (bf16_t*)d_ws;                                        // 4 MB
  bf16_t* qb = (bf16_t*)((char*)d_ws + (size_t)B_ROWS * N_BITS * 2); // 8 MB

  prep_kernel<<<3072, 256, 0, stream>>>(x, Q, xb, qb, out);

  dim3 grid(N_BITS / BN, B_ROWS / BM, KSPLIT);  // (16, 8, 8) = 1024 blocks
  qubo_kernel<<<grid, dim3(256), 0, stream>>>(xb, qb, out);
}